// Round 8
// baseline (857.826 us; speedup 1.0000x reference)
//
#include <hip/hip_runtime.h>
#include <math.h>

#define NROWS 16384
#define DDIM  2048
#define EEXP  64
#define RB    64               // rows per block
#define KD    64               // d per LDS chunk
#define NCHUNK (DDIM / KD)     // 32
#define XSTR  68               // x tile row stride (dwords): pad 4 -> rg groups on distinct banks
#define PSTR  66               // epilogue partial row stride

// smem floats: x bufs 2*64*68 = 8704 ; w bufs 2*64*64 = 8192 ; total 16896 (67.5 KB)
// epilogue reuse: part[16 waves][16 rows][66] = 16896
#define XOFF(b) ((b) * 4352)
#define WOFF(b) (8704 + (b) * 4096)

// 8 FMAs: scalar x (row i) against 8 experts
#define ROW_FMA(i, XS)                                   \
    acc[i][0] = fmaf(XS, wl.x, acc[i][0]);               \
    acc[i][1] = fmaf(XS, wl.y, acc[i][1]);               \
    acc[i][2] = fmaf(XS, wl.z, acc[i][2]);               \
    acc[i][3] = fmaf(XS, wl.w, acc[i][3]);               \
    acc[i][4] = fmaf(XS, wh.x, acc[i][4]);               \
    acc[i][5] = fmaf(XS, wh.y, acc[i][5]);               \
    acc[i][6] = fmaf(XS, wh.z, acc[i][6]);               \
    acc[i][7] = fmaf(XS, wh.w, acc[i][7]);

__global__ __launch_bounds__(1024, 4)
void router_kernel(const float* __restrict__ x,
                   const float* __restrict__ W,
                   const float* __restrict__ bias_v,
                   float* __restrict__ mask_out,
                   float* __restrict__ idx_out) {
    __shared__ __align__(16) float smem[16896];

    const int tid  = threadIdx.x;
    const int lane = tid & 63;
    const int wave = __builtin_amdgcn_readfirstlane(tid >> 6);
    const int eg   = lane & 7;     // experts 8*eg..8*eg+7
    const int rg   = lane >> 3;    // rows rg, rg+8, ..., rg+56
    const int row0 = blockIdx.x * RB;
    const int dw   = wave * 4;     // wave's 4-d slice within each 64-d chunk

    float acc[8][8];
#pragma unroll
    for (int i = 0; i < 8; ++i)
#pragma unroll
        for (int e = 0; e < 8; ++e) acc[i][e] = 0.0f;

    // staging: each of 1024 threads stages exactly 1 x-float4 + 1 w-float4 per chunk
    const int xr = tid >> 4;            // 0..63 (x row / w d-row)
    const int xq = tid & 15;            // quad within 64 d (or 64 e)
    const float*  xsrc = x + (size_t)(row0 + xr) * DDIM + xq * 4;
    const float4* wsrc = (const float4*)W + (size_t)xr * 16 + xq;  // + c*1024/chunk

    // prologue: chunk 0 -> buf 0
    {
        float4 a = *(const float4*)xsrc;
        float4 w = wsrc[0];
        *(float4*)(smem + XOFF(0) + xr * XSTR + xq * 4) = a;
        *(float4*)(smem + WOFF(0) + xr * 64   + xq * 4) = w;
    }

#pragma unroll 1
    for (int c = 0; c < NCHUNK; ++c) {
        __syncthreads();   // buf[c&1] staged; all waves done reading buf[(c+1)&1]

        const bool more = (c + 1) < NCHUNK;
        float4 px, pw;
        if (more) {        // prefetch chunk c+1 (a full chunk of compute to land)
            px = *(const float4*)(xsrc + (size_t)(c + 1) * KD);
            pw = wsrc[(size_t)(c + 1) * 1024];
        }

        const float* xb = smem + XOFF(c & 1) + rg * XSTR + dw;   // row i at +544*i
        const float* wb = smem + WOFF(c & 1) + dw * 64 + eg * 8;

#pragma unroll
        for (int hh = 0; hh < 2; ++hh) {     // two 2-d halves (keeps VGPR < 128)
            float2 xv0 = *(const float2*)(xb + 0*544 + 2*hh);
            float2 xv1 = *(const float2*)(xb + 1*544 + 2*hh);
            float2 xv2 = *(const float2*)(xb + 2*544 + 2*hh);
            float2 xv3 = *(const float2*)(xb + 3*544 + 2*hh);
            float2 xv4 = *(const float2*)(xb + 4*544 + 2*hh);
            float2 xv5 = *(const float2*)(xb + 5*544 + 2*hh);
            float2 xv6 = *(const float2*)(xb + 6*544 + 2*hh);
            float2 xv7 = *(const float2*)(xb + 7*544 + 2*hh);
#pragma unroll
            for (int dd = 0; dd < 2; ++dd) {
                const float* wrow = wb + (2*hh + dd) * 64;
                float4 wl = *(const float4*)(wrow);
                float4 wh = *(const float4*)(wrow + 4);
                if (dd == 0) {
                    ROW_FMA(0, xv0.x) ROW_FMA(1, xv1.x) ROW_FMA(2, xv2.x) ROW_FMA(3, xv3.x)
                    ROW_FMA(4, xv4.x) ROW_FMA(5, xv5.x) ROW_FMA(6, xv6.x) ROW_FMA(7, xv7.x)
                } else {
                    ROW_FMA(0, xv0.y) ROW_FMA(1, xv1.y) ROW_FMA(2, xv2.y) ROW_FMA(3, xv3.y)
                    ROW_FMA(4, xv4.y) ROW_FMA(5, xv5.y) ROW_FMA(6, xv6.y) ROW_FMA(7, xv7.y)
                }
            }
        }

        if (more) {        // write chunk c+1 into the other buffer
            const int nb = (c + 1) & 1;
            *(float4*)(smem + XOFF(nb) + xr * XSTR + xq * 4) = px;
            *(float4*)(smem + WOFF(nb) + xr * 64   + xq * 4) = pw;
        }
    }

    // ---- epilogue: 4 passes of 16 rows; 16-way cross-wave reduction in smem ----
    const float bias = bias_v[lane];
#pragma unroll 1
    for (int h = 0; h < 4; ++h) {
        __syncthreads();   // h=0: compute done; h>0: previous pass's reads done
#pragma unroll
        for (int ii = 0; ii < 2; ++ii) {
            const int i   = 2 * h + ii;         // acc row index (global row rg+8i)
            const int r16 = rg + 8 * ii;        // row within pass, 0..15
            float* pb = smem + wave * 1056 + r16 * PSTR + eg * 8;
            *(float2*)(pb + 0) = make_float2(acc[i][0], acc[i][1]);
            *(float2*)(pb + 2) = make_float2(acc[i][2], acc[i][3]);
            *(float2*)(pb + 4) = make_float2(acc[i][4], acc[i][5]);
            *(float2*)(pb + 6) = make_float2(acc[i][6], acc[i][7]);
        }
        __syncthreads();

        // wave w finishes row (16h + w)
        const int row = row0 + 16 * h + wave;
        float logit = bias;
#pragma unroll
        for (int p = 0; p < 16; ++p) logit += smem[p * 1056 + wave * PSTR + lane];

        float m = logit;
#pragma unroll
        for (int off = 32; off >= 1; off >>= 1)
            m = fmaxf(m, __shfl_xor(m, off));
        float ex = __expf(logit - m);
        float s = ex;
#pragma unroll
        for (int off = 32; off >= 1; off >>= 1)
            s += __shfl_xor(s, off);
        float gate = ex / s;

        float v1 = logit; int i1 = lane;
#pragma unroll
        for (int off = 32; off >= 1; off >>= 1) {
            float ov = __shfl_xor(v1, off);
            int   oi = __shfl_xor(i1, off);
            if (ov > v1 || (ov == v1 && oi < i1)) { v1 = ov; i1 = oi; }
        }
        float v2 = (lane == i1) ? -INFINITY : logit; int i2 = lane;
#pragma unroll
        for (int off = 32; off >= 1; off >>= 1) {
            float ov = __shfl_xor(v2, off);
            int   oi = __shfl_xor(i2, off);
            if (ov > v2 || (ov == v2 && oi < i2)) { v2 = ov; i2 = oi; }
        }

        float outv = (lane == i1 || lane == i2) ? gate : 0.0f;
        mask_out[(size_t)row * EEXP + lane] = outv;
        if (lane == 0) {
            idx_out[row * 2 + 0] = (float)i1;
            idx_out[row * 2 + 1] = (float)i2;
        }
    }
}

extern "C" void kernel_launch(void* const* d_in, const int* in_sizes, int n_in,
                              void* d_out, int out_size, void* d_ws, size_t ws_size,
                              hipStream_t stream) {
    const float* x = (const float*)d_in[0];
    const float* W = (const float*)d_in[1];
    const float* b = (const float*)d_in[2];
    float* mask_out = (float*)d_out;
    float* idx_out  = mask_out + (size_t)NROWS * EEXP;

    dim3 grid(NROWS / RB);   // 256 blocks -> 1 block/CU, 16 waves/CU (4/SIMD)
    dim3 block(1024);
    router_kernel<<<grid, block, 0, stream>>>(x, W, b, mask_out, idx_out);
}

// Round 9
// 856.615 us; speedup vs baseline: 1.0014x; 1.0014x over previous
//
#include <hip/hip_runtime.h>
#include <math.h>

#define NROWS 16384
#define DDIM  2048
#define EEXP  64
#define RB    64               // rows per block
#define KD    64               // d per LDS chunk
#define NCHUNK (DDIM / KD)     // 32
#define XSTR  68               // x tile row stride (dwords): pad 4 -> rg groups on distinct banks
#define PSTR  66               // epilogue partial row stride

// smem floats: x bufs 2*64*68 = 8704 ; w bufs 2*64*64 = 8192 ; total 16896 (67.5 KB)
// epilogue reuse: part[16 waves][16 rows][66] = 16896
#define XOFF(b) ((b) * 4352)
#define WOFF(b) (8704 + (b) * 4096)

// 8 FMAs: scalar x (row i) against 8 experts
#define ROW_FMA(i, XS)                                   \
    acc[i][0] = fmaf(XS, wl.x, acc[i][0]);               \
    acc[i][1] = fmaf(XS, wl.y, acc[i][1]);               \
    acc[i][2] = fmaf(XS, wl.z, acc[i][2]);               \
    acc[i][3] = fmaf(XS, wl.w, acc[i][3]);               \
    acc[i][4] = fmaf(XS, wh.x, acc[i][4]);               \
    acc[i][5] = fmaf(XS, wh.y, acc[i][5]);               \
    acc[i][6] = fmaf(XS, wh.z, acc[i][6]);               \
    acc[i][7] = fmaf(XS, wh.w, acc[i][7]);

// NOTE (measured R2/R5/R6/R8): __launch_bounds__ arg2 on this toolchain behaves
// as CUDA min-BLOCKS-per-CU. (1024,4) capped VGPR at 64 -> acc spilled (740us).
// (1024,1) -> cap 128, live set ~106, no spill.
__global__ __launch_bounds__(1024, 1)
void router_kernel(const float* __restrict__ x,
                   const float* __restrict__ W,
                   const float* __restrict__ bias_v,
                   float* __restrict__ mask_out,
                   float* __restrict__ idx_out) {
    __shared__ __align__(16) float smem[16896];

    const int tid  = threadIdx.x;
    const int lane = tid & 63;
    const int wave = __builtin_amdgcn_readfirstlane(tid >> 6);
    const int eg   = lane & 7;     // experts 8*eg..8*eg+7
    const int rg   = lane >> 3;    // rows rg, rg+8, ..., rg+56
    const int row0 = blockIdx.x * RB;
    const int dw   = wave * 4;     // wave's 4-d slice within each 64-d chunk

    float acc[8][8];
#pragma unroll
    for (int i = 0; i < 8; ++i)
#pragma unroll
        for (int e = 0; e < 8; ++e) acc[i][e] = 0.0f;

    // staging: each of 1024 threads stages exactly 1 x-float4 + 1 w-float4 per chunk
    const int xr = tid >> 4;            // 0..63 (x row / w d-row)
    const int xq = tid & 15;            // quad within 64 d (or 64 e)
    const float*  xsrc = x + (size_t)(row0 + xr) * DDIM + xq * 4;
    const float4* wsrc = (const float4*)W + (size_t)xr * 16 + xq;  // + c*1024/chunk

    // prologue: chunk 0 -> buf 0
    {
        float4 a = *(const float4*)xsrc;
        float4 w = wsrc[0];
        *(float4*)(smem + XOFF(0) + xr * XSTR + xq * 4) = a;
        *(float4*)(smem + WOFF(0) + xr * 64   + xq * 4) = w;
    }

#pragma unroll 1
    for (int c = 0; c < NCHUNK; ++c) {
        __syncthreads();   // buf[c&1] staged; all waves done reading buf[(c+1)&1]

        const bool more = (c + 1) < NCHUNK;
        float4 px, pw;
        if (more) {        // prefetch chunk c+1 (a full chunk of compute to land)
            px = *(const float4*)(xsrc + (size_t)(c + 1) * KD);
            pw = wsrc[(size_t)(c + 1) * 1024];
        }

        const float* xb = smem + XOFF(c & 1) + rg * XSTR + dw;   // row i at +544*i
        const float* wb = smem + WOFF(c & 1) + dw * 64 + eg * 8;

#pragma unroll
        for (int hh = 0; hh < 2; ++hh) {     // two 2-d halves (keeps live VGPRs low)
            float2 xv0 = *(const float2*)(xb + 0*544 + 2*hh);
            float2 xv1 = *(const float2*)(xb + 1*544 + 2*hh);
            float2 xv2 = *(const float2*)(xb + 2*544 + 2*hh);
            float2 xv3 = *(const float2*)(xb + 3*544 + 2*hh);
            float2 xv4 = *(const float2*)(xb + 4*544 + 2*hh);
            float2 xv5 = *(const float2*)(xb + 5*544 + 2*hh);
            float2 xv6 = *(const float2*)(xb + 6*544 + 2*hh);
            float2 xv7 = *(const float2*)(xb + 7*544 + 2*hh);
#pragma unroll
            for (int dd = 0; dd < 2; ++dd) {
                const float* wrow = wb + (2*hh + dd) * 64;
                float4 wl = *(const float4*)(wrow);
                float4 wh = *(const float4*)(wrow + 4);
                if (dd == 0) {
                    ROW_FMA(0, xv0.x) ROW_FMA(1, xv1.x) ROW_FMA(2, xv2.x) ROW_FMA(3, xv3.x)
                    ROW_FMA(4, xv4.x) ROW_FMA(5, xv5.x) ROW_FMA(6, xv6.x) ROW_FMA(7, xv7.x)
                } else {
                    ROW_FMA(0, xv0.y) ROW_FMA(1, xv1.y) ROW_FMA(2, xv2.y) ROW_FMA(3, xv3.y)
                    ROW_FMA(4, xv4.y) ROW_FMA(5, xv5.y) ROW_FMA(6, xv6.y) ROW_FMA(7, xv7.y)
                }
            }
        }

        if (more) {        // write chunk c+1 into the other buffer
            const int nb = (c + 1) & 1;
            *(float4*)(smem + XOFF(nb) + xr * XSTR + xq * 4) = px;
            *(float4*)(smem + WOFF(nb) + xr * 64   + xq * 4) = pw;
        }
    }

    // ---- epilogue: 4 passes of 16 rows; 16-way cross-wave reduction in smem ----
    const float bias = bias_v[lane];
#pragma unroll 1
    for (int h = 0; h < 4; ++h) {
        __syncthreads();   // h=0: compute done; h>0: previous pass's reads done
#pragma unroll
        for (int ii = 0; ii < 2; ++ii) {
            const int i   = 2 * h + ii;         // acc row index (global row rg+8i)
            const int r16 = rg + 8 * ii;        // row within pass, 0..15
            float* pb = smem + wave * 1056 + r16 * PSTR + eg * 8;
            *(float2*)(pb + 0) = make_float2(acc[i][0], acc[i][1]);
            *(float2*)(pb + 2) = make_float2(acc[i][2], acc[i][3]);
            *(float2*)(pb + 4) = make_float2(acc[i][4], acc[i][5]);
            *(float2*)(pb + 6) = make_float2(acc[i][6], acc[i][7]);
        }
        __syncthreads();

        // wave w finishes row (16h + w)
        const int row = row0 + 16 * h + wave;
        float logit = bias;
#pragma unroll
        for (int p = 0; p < 16; ++p) logit += smem[p * 1056 + wave * PSTR + lane];

        float m = logit;
#pragma unroll
        for (int off = 32; off >= 1; off >>= 1)
            m = fmaxf(m, __shfl_xor(m, off));
        float ex = __expf(logit - m);
        float s = ex;
#pragma unroll
        for (int off = 32; off >= 1; off >>= 1)
            s += __shfl_xor(s, off);
        float gate = ex / s;

        float v1 = logit; int i1 = lane;
#pragma unroll
        for (int off = 32; off >= 1; off >>= 1) {
            float ov = __shfl_xor(v1, off);
            int   oi = __shfl_xor(i1, off);
            if (ov > v1 || (ov == v1 && oi < i1)) { v1 = ov; i1 = oi; }
        }
        float v2 = (lane == i1) ? -INFINITY : logit; int i2 = lane;
#pragma unroll
        for (int off = 32; off >= 1; off >>= 1) {
            float ov = __shfl_xor(v2, off);
            int   oi = __shfl_xor(i2, off);
            if (ov > v2 || (ov == v2 && oi < i2)) { v2 = ov; i2 = oi; }
        }

        float outv = (lane == i1 || lane == i2) ? gate : 0.0f;
        mask_out[(size_t)row * EEXP + lane] = outv;
        if (lane == 0) {
            idx_out[row * 2 + 0] = (float)i1;
            idx_out[row * 2 + 1] = (float)i2;
        }
    }
}

extern "C" void kernel_launch(void* const* d_in, const int* in_sizes, int n_in,
                              void* d_out, int out_size, void* d_ws, size_t ws_size,
                              hipStream_t stream) {
    const float* x = (const float*)d_in[0];
    const float* W = (const float*)d_in[1];
    const float* b = (const float*)d_in[2];
    float* mask_out = (float*)d_out;
    float* idx_out  = mask_out + (size_t)NROWS * EEXP;

    dim3 grid(NROWS / RB);   // 256 blocks -> 1 block/CU, 16 waves/CU (4/SIMD)
    dim3 block(1024);
    router_kernel<<<grid, block, 0, stream>>>(x, W, b, mask_out, idx_out);
}